// Round 8
// baseline (687.559 us; speedup 1.0000x reference)
//
#include <hip/hip_runtime.h>

// Problem constants: T=512, B=64, D=1024, fp32.
#define T_DIM   512
#define BD4     16384          // B*D/4 (float4 columns)
#define CHUNKS  16
#define CHUNK_T 32             // T_DIM / CHUNKS
#define CB      64             // col-blocks per chunk = BD4/256
#define NBLOCKS (CHUNKS * CB)  // 1024 — all co-resident (4096 waves < 8192 cap)

// Native clang vector for nontemporal stores (HIP float4 is a class type,
// rejected by __builtin_nontemporal_store).
typedef float nfloat4 __attribute__((ext_vector_type(4)));

__device__ __forceinline__ float sigmoid_fast(float x) {
    // 1 / (1 + e^-x) via hw exp2 + hw rcp (~2 ULP, fine vs f32 reference)
    float e = __expf(-x);
    return __builtin_amdgcn_rcpf(1.0f + e);
}

// ws layout (bytes):
//   [0)        u32 vid counter
//   [256)      u32 flags[(CHUNKS-1)*CB] = 960 flags
//   [4096)     float4 sums[(CHUNKS-1)*BD4] = 3.75 MiB
// ws is poisoned 0xAA before every launch -> init kernel zeroes ctr+flags.
__global__ __launch_bounds__(256)
void SumGoalHistory_init(unsigned* __restrict__ ws) {
    for (int k = threadIdx.x; k < 1024; k += 256) ws[k] = 0u;
}

// Single-pass decoupled-lookback scan over T-chunks.
// Block role from a dynamic vid (atomicAdd) so vid order == scheduling order
// -> lookback is deadlock-free without any dispatch-order assumption.
__global__ __launch_bounds__(256)
void SumGoalHistory_fused(const float4* __restrict__ goal,
                          const float4* __restrict__ init,
                          float4* __restrict__ out,
                          unsigned* __restrict__ ctr,
                          unsigned* __restrict__ flags,
                          float4* __restrict__ sums) {
    __shared__ unsigned s_vid;
    if (threadIdx.x == 0) s_vid = atomicAdd(ctr, 1u);
    __syncthreads();
    const unsigned vid = s_vid;
    const int c = vid >> 6;                 // chunk        (uniform per block)
    const int j = vid & (CB - 1);           // col-block
    const int i = j * 256 + threadIdx.x;    // float4 column

    // ---- phase 1: own chunk sum (reads goal once, cold HBM; primes L3) ----
    const float4* p = goal + (size_t)c * CHUNK_T * BD4 + i;
    float sx = 0.f, sy = 0.f, sz = 0.f, sw = 0.f;
    #pragma unroll 8
    for (int t = 0; t < CHUNK_T; ++t) {
        float4 v = p[(size_t)t * BD4];
        sx += v.x; sy += v.y; sz += v.z; sw += v.w;
    }

    // ---- publish aggregate (chunks 0..CHUNKS-2; chunk 15's agg unused) ----
    if (c < CHUNKS - 1) {
        sums[(size_t)c * BD4 + i] = make_float4(sx, sy, sz, sw);
        __threadfence();                    // agent-scope release of the stores
        __syncthreads();                    // all 4 waves' stores fenced
        if (threadIdx.x == 0)
            __hip_atomic_store(&flags[vid], 1u,
                               __ATOMIC_RELEASE, __HIP_MEMORY_SCOPE_AGENT);
    }

    // ---- lookback: offset = init + sum of predecessor aggregates ----
    float4 a = init[i];
    float ax = a.x, ay = a.y, az = a.z, aw = a.w;
    for (int cc = 0; cc < c; ++cc) {
        const unsigned f = cc * CB + j;
        while (__hip_atomic_load(&flags[f],
                                 __ATOMIC_ACQUIRE, __HIP_MEMORY_SCOPE_AGENT) == 0u)
            __builtin_amdgcn_s_sleep(1);
        float4 s = sums[(size_t)cc * BD4 + i];
        ax += s.x; ay += s.y; az += s.z; aw += s.w;
    }

    // ---- phase 2: rescan own slice (L3-hot re-read), sigmoid, nt-store ----
    nfloat4* o = (nfloat4*)out + (size_t)c * CHUNK_T * BD4 + i;
    #pragma unroll 4
    for (int t = 0; t < CHUNK_T; ++t) {
        float4 v = p[(size_t)t * BD4];
        ax += v.x; ay += v.y; az += v.z; aw += v.w;
        nfloat4 r;
        r.x = sigmoid_fast(ax);
        r.y = sigmoid_fast(ay);
        r.z = sigmoid_fast(az);
        r.w = sigmoid_fast(aw);
        // nt: outputs never re-read; keep them out of L3 so goal stays hot
        __builtin_nontemporal_store(r, o + (size_t)t * BD4);
    }

    if (c == CHUNKS - 1) {
        // final_state written twice: d_out layout = outputs | final | final
        float4 fv = make_float4(ax, ay, az, aw);
        float4* fin = out + (size_t)T_DIM * BD4;
        fin[i] = fv;
        fin[BD4 + i] = fv;
    }
}

extern "C" void kernel_launch(void* const* d_in, const int* in_sizes, int n_in,
                              void* d_out, int out_size, void* d_ws, size_t ws_size,
                              hipStream_t stream) {
    const float4* goal = (const float4*)d_in[0];   // [T, B, D] f32
    const float4* init = (const float4*)d_in[1];   // [1, B, D] f32
    float4* out = (float4*)d_out;                  // outputs | final | final

    unsigned* ctr   = (unsigned*)d_ws;
    unsigned* flags = (unsigned*)((char*)d_ws + 256);
    float4*   sums  = (float4*)((char*)d_ws + 4096);

    SumGoalHistory_init<<<1, 256, 0, stream>>>((unsigned*)d_ws);
    SumGoalHistory_fused<<<NBLOCKS, 256, 0, stream>>>(goal, init, out,
                                                      ctr, flags, sums);
}

// Round 9
// 508.405 us; speedup vs baseline: 1.3524x; 1.3524x over previous
//
#include <hip/hip_runtime.h>
#include <hip/hip_cooperative_groups.h>

namespace cg = cooperative_groups;

// Problem constants: T=512, B=64, D=1024, fp32.
#define T_DIM   512
#define BD4     16384          // B*D/4 (float4 columns)
#define CHUNKS  16
#define CHUNK_T 32             // T_DIM / CHUNKS
#define CB      64             // col-blocks per chunk = BD4/256
#define NBLOCKS (CHUNKS * CB)  // 1024 blocks * 4 waves = 4096 waves, co-resident

// Native clang vector for nontemporal stores (HIP float4 is a class type,
// rejected by __builtin_nontemporal_store).
typedef float nfloat4 __attribute__((ext_vector_type(4)));

__device__ __forceinline__ float sigmoid_fast(float x) {
    // 1 / (1 + e^-x) via hw exp2 + hw rcp (~2 ULP, fine vs f32 reference)
    float e = __expf(-x);
    return __builtin_amdgcn_rcpf(1.0f + e);
}

// Single cooperative kernel:
//   P1: blocks of chunks 0..14 compute per-column chunk sums (cold HBM read,
//       primes L3; R8 counters proved the P2 re-read then hits L3).
//   grid.sync() — replaces R8's spin-lookback (which cost ~500us in
//       cross-XCD flag polling; VALUBusy was 1.3%).
//   P2: offset = init + prefix of chunk sums (3.75MB, L2/L3-hot), then
//       32-step scan + sigmoid + nontemporal store.
__global__ __launch_bounds__(256)
void SumGoalHistory_coop(const float4* __restrict__ goal,
                         const float4* __restrict__ init,
                         float4* __restrict__ out,
                         float4* __restrict__ sums) {
    const int c = blockIdx.x >> 6;          // chunk (uniform per block)
    const int j = blockIdx.x & (CB - 1);    // col-block
    const int i = j * 256 + threadIdx.x;    // float4 column

    const float4* p = goal + (size_t)c * CHUNK_T * BD4 + i;

    // ---- phase 1: chunk sums for chunks 0..14 (chunk 15's agg unused) ----
    if (c < CHUNKS - 1) {
        float sx = 0.f, sy = 0.f, sz = 0.f, sw = 0.f;
        #pragma unroll 8
        for (int t = 0; t < CHUNK_T; ++t) {
            float4 v = p[(size_t)t * BD4];
            sx += v.x; sy += v.y; sz += v.z; sw += v.w;
        }
        sums[(size_t)c * BD4 + i] = make_float4(sx, sy, sz, sw);
    }

    // Release our sums stores to device scope, then grid-wide barrier.
    __threadfence();
    cg::this_grid().sync();

    // ---- lookback: offset = init + sum of predecessor aggregates ----
    float4 a = init[i];
    float ax = a.x, ay = a.y, az = a.z, aw = a.w;
    for (int cc = 0; cc < c; ++cc) {
        float4 s = sums[(size_t)cc * BD4 + i];
        ax += s.x; ay += s.y; az += s.z; aw += s.w;
    }

    // ---- phase 2: rescan own slice (L3-hot; chunk 15 reads cold), store ----
    nfloat4* o = (nfloat4*)out + (size_t)c * CHUNK_T * BD4 + i;
    #pragma unroll 4
    for (int t = 0; t < CHUNK_T; ++t) {
        float4 v = p[(size_t)t * BD4];
        ax += v.x; ay += v.y; az += v.z; aw += v.w;
        nfloat4 r;
        r.x = sigmoid_fast(ax);
        r.y = sigmoid_fast(ay);
        r.z = sigmoid_fast(az);
        r.w = sigmoid_fast(aw);
        // nt: outputs never re-read; keep them out of L3 so goal stays hot
        __builtin_nontemporal_store(r, o + (size_t)t * BD4);
    }

    if (c == CHUNKS - 1) {
        // final_state written twice: d_out layout = outputs | final | final
        float4 fv = make_float4(ax, ay, az, aw);
        float4* fin = out + (size_t)T_DIM * BD4;
        fin[i] = fv;
        fin[BD4 + i] = fv;
    }
}

extern "C" void kernel_launch(void* const* d_in, const int* in_sizes, int n_in,
                              void* d_out, int out_size, void* d_ws, size_t ws_size,
                              hipStream_t stream) {
    const float4* goal = (const float4*)d_in[0];   // [T, B, D] f32
    const float4* init = (const float4*)d_in[1];   // [1, B, D] f32
    float4* out  = (float4*)d_out;                 // outputs | final | final
    float4* sums = (float4*)d_ws;                  // 3.75 MiB chunk aggregates

    void* args[] = { (void*)&goal, (void*)&init, (void*)&out, (void*)&sums };
    hipLaunchCooperativeKernel((const void*)SumGoalHistory_coop,
                               dim3(NBLOCKS), dim3(256), args, 0, stream);
}

// Round 10
// 230.172 us; speedup vs baseline: 2.9872x; 2.2088x over previous
//
#include <hip/hip_runtime.h>

// Problem constants: T=512, B=64, D=1024, fp32.
#define T_DIM 512
#define BD    65536            // B*D floats per time slice

__device__ __forceinline__ float sigmoid_fast(float x) {
    // 1 / (1 + e^-x) via hw exp2 + hw rcp (~2 ULP, fine vs f32 reference)
    float e = __expf(-x);
    return __builtin_amdgcn_rcpf(1.0f + e);
}

// Single-pass scan: one thread per (b,d) scalar column. Each goal byte is
// read from HBM exactly once; outputs written once -> 271 MB, the traffic
// minimum. No inter-block sync (R8 lookback = 560us, R9 grid.sync = 343us:
// both global-sync structures are latency disasters on 8 non-coherent XCDs).
// MLP comes from unroll-32: 32 independent loads in flight per wave
// (32 KB/CU at 4 waves/CU -> ~36 GB/s/CU streamable > 24.6 needed).
__global__ __launch_bounds__(128)
void SumGoalHistory_onepass(const float* __restrict__ goal,
                            const float* __restrict__ init,
                            float* __restrict__ out) {
    const int col = blockIdx.x * 128 + threadIdx.x;   // [0, BD)

    float acc = init[col];
    const float* p = goal + col;
    float*       o = out  + col;

    #pragma unroll 32
    for (int t = 0; t < T_DIM; ++t) {
        acc += p[(size_t)t * BD];
        // nt: outputs never re-read; don't pollute L2/L3
        __builtin_nontemporal_store(sigmoid_fast(acc), o + (size_t)t * BD);
    }

    // final_state written twice: d_out layout = outputs | final | final
    float* fin = out + (size_t)T_DIM * BD;
    fin[col] = acc;
    fin[BD + col] = acc;
}

extern "C" void kernel_launch(void* const* d_in, const int* in_sizes, int n_in,
                              void* d_out, int out_size, void* d_ws, size_t ws_size,
                              hipStream_t stream) {
    const float* goal = (const float*)d_in[0];   // [T, B, D] f32
    const float* init = (const float*)d_in[1];   // [1, B, D] f32
    float* out = (float*)d_out;                  // outputs | final | final

    SumGoalHistory_onepass<<<BD / 128, 128, 0, stream>>>(goal, init, out);
}